// Round 6
// baseline (180.971 us; speedup 1.0000x reference)
//
#include <hip/hip_runtime.h>
#include <math.h>

// R6: weights via wave-uniform s_load. Recon kernel (92 blocks) materializes
// all 4 reconstructed tensors TRANSPOSED (f[c][oc]) so adder loops fetch
// per-iteration weights as one s_load_dwordx8/x4 (scalar pipe) instead of
// 8x/4x ds_read_b32 broadcasts (LDS pipe was the front/back bottleneck).
// minmax folded into recon (each block rescans its tensor: L2-hot, ~free).
// KL partials in disjoint slots (no zero-before-atomic dependency).

#define HW 784      // 28*28
#define NB 4
#define STAGE 100

// ---------------- wave/block reduction helpers (wave64) --------------------
__device__ __forceinline__ float wredMax(float v){
  for (int o = 32; o > 0; o >>= 1) v = fmaxf(v, __shfl_down(v, o, 64));
  return v;
}
__device__ __forceinline__ float wredMin(float v){
  for (int o = 32; o > 0; o >>= 1) v = fminf(v, __shfl_down(v, o, 64));
  return v;
}
__device__ __forceinline__ double wredSumD(double v){
  for (int o = 32; o > 0; o >>= 1) v += __shfl_down(v, o, 64);
  return v;
}

// blockDim = 256 (4 waves)
__device__ float blockMin4(float v){
  __shared__ float shn[4];
  __syncthreads();
  v = wredMin(v);
  if ((threadIdx.x & 63) == 0) shn[threadIdx.x >> 6] = v;
  __syncthreads();
  return fminf(fminf(shn[0], shn[1]), fminf(shn[2], shn[3]));
}
__device__ float blockMax4(float v){
  __shared__ float shx[4];
  __syncthreads();
  v = wredMax(v);
  if ((threadIdx.x & 63) == 0) shx[threadIdx.x >> 6] = v;
  __syncthreads();
  return fmaxf(fmaxf(shx[0], shx[1]), fmaxf(shx[2], shx[3]));
}

// ---- per-block BN stats: 4 channels, sum+sumsq, double atomics (256 thr) --
__device__ void stats4(float v0, float v1, float v2, float v3,
                       double* sumP, double* sqP, int oc0){
  __shared__ double sred[4][8];
  __syncthreads();
  const int w = threadIdx.x >> 6;
  float vv[4] = {v0, v1, v2, v3};
  #pragma unroll
  for (int i = 0; i < 4; i++){
    double d = (double)vv[i];
    double s = wredSumD(d);
    double q = wredSumD(d * d);
    if ((threadIdx.x & 63) == 0){ sred[w][i] = s; sred[w][4 + i] = q; }
  }
  __syncthreads();
  if (threadIdx.x < 8){
    double tot = sred[0][threadIdx.x] + sred[1][threadIdx.x]
               + sred[2][threadIdx.x] + sred[3][threadIdx.x];
    int i = threadIdx.x & 3;
    if (threadIdx.x < 4) atomicAdd(&sumP[oc0 + i], tot);
    else                 atomicAdd(&sqP[oc0 + i],  tot);
  }
}
__device__ void stats2(float v0, float v1, double* sumP, double* sqP, int oc0){
  __shared__ double sred2[4][4];
  __syncthreads();
  const int w = threadIdx.x >> 6;
  float vv[2] = {v0, v1};
  #pragma unroll
  for (int i = 0; i < 2; i++){
    double d = (double)vv[i];
    double s = wredSumD(d);
    double q = wredSumD(d * d);
    if ((threadIdx.x & 63) == 0){ sred2[w][i] = s; sred2[w][2 + i] = q; }
  }
  __syncthreads();
  if (threadIdx.x < 4){
    double tot = sred2[0][threadIdx.x] + sred2[1][threadIdx.x]
               + sred2[2][threadIdx.x] + sred2[3][threadIdx.x];
    int i = threadIdx.x & 1;
    if (threadIdx.x < 2) atomicAdd(&sumP[oc0 + i], tot);
    else                 atomicAdd(&sqP[oc0 + i],  tot);
  }
}

// ---- bin reconstruction (reference op order; exact bin indices) -----------
__device__ __forceinline__ float reconv(float vv, float mn, float rng,
                                        const float* saff){
  float q = (vv - mn) / rng * 100.0f;
  int idx = (int)floorf(q);
  float nv = 0.0f;
  if (idx < STAGE){
    int ci = idx < 0 ? 0 : (idx > STAGE - 1 ? STAGE - 1 : idx);
    nv = vv * saff[ci];
  }
  return nv;
}

// --------------- K1: recon (transposed) + KL partials + zero stats ---------
// grid = 92 blocks: t0 [0,32) t1 [32,40) t2 [40,76) t3 [76,92); each block
// handles a 1024-elem slice, rescans its whole tensor for min/max.
// dstat layout (doubles): [0:256) ds_sum [256:512) ds_sq [512:576) bn1_s
//   [576:640) bn1_q [640:704) bn2_s [704:768) bn2_q [768:1024) bn3_s
//   [1024:1280) bn3_q [1280:1648) kl partials: blk*4 + {se,sel,sef,sq}
__global__ __launch_bounds__(256) void reconkl_kernel(
    const float* __restrict__ w_ds, const float* __restrict__ a_ds,
    const float* __restrict__ lap_ds, float* __restrict__ f_dsT,
    const float* __restrict__ w_c1, const float* __restrict__ a_c1,
    const float* __restrict__ lap_c1, float* __restrict__ f_c1T,
    const float* __restrict__ w_c2, const float* __restrict__ a_c2,
    const float* __restrict__ lap_c2, float* __restrict__ f_c2,
    const float* __restrict__ w_c3, const float* __restrict__ a_c3,
    const float* __restrict__ lap_c3, float* __restrict__ f_c3T,
    double* __restrict__ dstat)
{
  const int blk = blockIdx.x, t = threadIdx.x;
  // zero BN-stat region [0:1280): 92 blocks x 14 doubles covers it
  if (t < 14 && blk * 14 + t < 1280) dstat[blk * 14 + t] = 0.0;

  int tens, slice;
  if      (blk < 32){ tens = 0; slice = blk; }
  else if (blk < 40){ tens = 1; slice = blk - 32; }
  else if (blk < 76){ tens = 2; slice = blk - 40; }
  else              { tens = 3; slice = blk - 76; }
  const float *w, *aff, *lap; int n;
  if      (tens == 0){ w = w_ds; aff = a_ds; lap = lap_ds; n = 32768; }
  else if (tens == 1){ w = w_c1; aff = a_c1; lap = lap_c1; n = 8192; }
  else if (tens == 2){ w = w_c2; aff = a_c2; lap = lap_c2; n = 36864; }
  else               { w = w_c3; aff = a_c3; lap = lap_c3; n = 16384; }

  __shared__ float saff[STAGE];
  if (t < STAGE) saff[t] = aff[t];

  // full-tensor min/max (redundant across slice-blocks; tensors are L2-hot)
  const float4* w4 = (const float4*)w;
  float mn = 3.402823466e38f, mx = -3.402823466e38f;
  for (int i = t; i < (n >> 2); i += 256){
    float4 v = w4[i];
    mn = fminf(mn, fminf(fminf(v.x, v.y), fminf(v.z, v.w)));
    mx = fmaxf(mx, fmaxf(fmaxf(v.x, v.y), fmaxf(v.z, v.w)));
  }
  mn = blockMin4(mn); mx = blockMax4(mx);
  const float rng = mx - mn;

  // recon 1024-elem slice (transposed store) + KL partial sums
  float se = 0, sel = 0, sef = 0, sq = 0;
  const int k0 = slice * 1024;
  for (int j = t; j < 1024; j += 256){
    int k = k0 + j;
    float nv = reconv(w[k], mn, rng, saff);
    if      (tens == 0){ int oc = k >> 7, c = k & 127; f_dsT[c * 256 + oc] = nv; }
    else if (tens == 1){ int oc = k >> 7, c = k & 127; f_c1T[c * 64 + oc] = nv; }
    else if (tens == 2){ f_c2[k] = nv; }
    else               { int oc = k >> 6, c = k & 63;  f_c3T[c * 256 + oc] = nv; }
    float l = lap[k];
    float e = expf(l);
    se += e; sel += e * l; sef += e * nv; sq += expf(nv);
  }
  // block-reduce the 4 sums, plain store to this block's slot
  __shared__ double kls[4][4];
  __syncthreads();
  const int wv = t >> 6;
  double a0 = wredSumD((double)se);
  double a1 = wredSumD((double)sel);
  double a2 = wredSumD((double)sef);
  double a3 = wredSumD((double)sq);
  if ((t & 63) == 0){ kls[wv][0]=a0; kls[wv][1]=a1; kls[wv][2]=a2; kls[wv][3]=a3; }
  __syncthreads();
  if (t < 4){
    double tot = kls[0][t] + kls[1][t] + kls[2][t] + kls[3][t];
    dstat[1280 + blk * 4 + t] = tot;
  }
}

// --------------- K2: front — adder_ds + (adder_c1 fused with PEG) ----------
// blocks [0,512): adder_ds, 8 oc, 196-px chunks; weights: s_load from f_dsT
// blocks [512,768): adder_c1+peg, 4 oc, 7-row tile; weights: f_c1T + peg_w
__global__ __launch_bounds__(256) void front_kernel(
    const float* __restrict__ x, const float* __restrict__ f_dsT,
    const float* __restrict__ f_c1T, const float* __restrict__ peg_w,
    float* __restrict__ A, float* __restrict__ T2, double* __restrict__ dS)
{
  const int t = threadIdx.x;
  if (blockIdx.x < 512){
    const int a = blockIdx.x;
    const int chunk = a & 3, og = (a >> 2) & 31, b = a >> 7;
    const int oc0 = og * 8;
    const int px = chunk * 196 + t;
    float v0=0,v1=0,v2=0,v3=0,v4=0,v5=0,v6=0,v7=0;
    if (t < 196){
      const float* xp = x + (size_t)b * 128 * HW + px;
      const float* wp = f_dsT + oc0;          // row c: wp + c*256, 8 contig
      float c0=0,c1=0,c2=0,c3=0,c4=0,c5=0,c6=0,c7=0;
      #pragma unroll 4
      for (int c = 0; c < 128; c++){
        float xv = xp[(size_t)c * HW];
        const float* wr = wp + c * 256;       // block-uniform -> s_load
        c0 += fabsf(xv - wr[0]);
        c1 += fabsf(xv - wr[1]);
        c2 += fabsf(xv - wr[2]);
        c3 += fabsf(xv - wr[3]);
        c4 += fabsf(xv - wr[4]);
        c5 += fabsf(xv - wr[5]);
        c6 += fabsf(xv - wr[6]);
        c7 += fabsf(xv - wr[7]);
      }
      v0=-c0; v1=-c1; v2=-c2; v3=-c3; v4=-c4; v5=-c5; v6=-c6; v7=-c7;
      float* op = A + ((size_t)(b * 256 + oc0)) * HW + px;
      op[0]=v0; op[HW]=v1; op[2*HW]=v2; op[3*HW]=v3;
      op[4*HW]=v4; op[5*HW]=v5; op[6*HW]=v6; op[7*HW]=v7;
    }
    stats4(v0, v1, v2, v3, dS + 0, dS + 256, oc0);
    stats4(v4, v5, v6, v7, dS + 0, dS + 256, oc0 + 4);
  } else {
    const int a = blockIdx.x - 512;
    const int rc = a & 3, og = (a >> 2) & 15, b = a >> 6;
    const int oc0 = og * 4;
    __shared__ float sT1[4][256];
    if (t < 252){
      const int rr = t / 28;
      const int col = t - rr * 28;
      const int wr = rc * 7 - 1 + rr;
      float tv0 = 0, tv1 = 0, tv2 = 0, tv3 = 0;
      if (wr >= 0 && wr < 28){
        const float* xp = x + (size_t)b * 128 * HW + wr * 28 + col;
        const float* wp = f_c1T + oc0;        // row c: wp + c*64, 4 contig
        float c0 = 0, c1 = 0, c2 = 0, c3 = 0;
        #pragma unroll 4
        for (int c = 0; c < 128; c++){
          float xv = xp[(size_t)c * HW];
          const float* wrp = wp + c * 64;     // block-uniform -> s_load
          c0 += fabsf(xv - wrp[0]);
          c1 += fabsf(xv - wrp[1]);
          c2 += fabsf(xv - wrp[2]);
          c3 += fabsf(xv - wrp[3]);
        }
        tv0 = -c0; tv1 = -c1; tv2 = -c2; tv3 = -c3;
      }
      sT1[0][t] = tv0; sT1[1][t] = tv1; sT1[2][t] = tv2; sT1[3][t] = tv3;
    }
    __syncthreads();
    float v0 = 0, v1 = 0, v2 = 0, v3 = 0;
    if (t < 196){
      const int r = t / 28, col = t - r * 28;
      const float* wp0 = peg_w + oc0 * 9;     // block-uniform -> s_load
      const float* wp1 = wp0 + 9;
      const float* wp2 = wp0 + 18;
      const float* wp3 = wp0 + 27;
      float c0 = 0, c1 = 0, c2 = 0, c3 = 0;
      #pragma unroll
      for (int ky = 0; ky < 3; ky++){
        #pragma unroll
        for (int kx = 0; kx < 3; kx++){
          int cc = col + kx - 1;
          bool ok = (cc >= 0) && (cc < 28);
          int idx = ok ? ((r + ky) * 28 + cc) : 0;
          float p0 = ok ? sT1[0][idx] : 0.0f;
          float p1 = ok ? sT1[1][idx] : 0.0f;
          float p2 = ok ? sT1[2][idx] : 0.0f;
          float p3 = ok ? sT1[3][idx] : 0.0f;
          int wk = ky * 3 + kx;
          c0 += fabsf(p0 - wp0[wk]);
          c1 += fabsf(p1 - wp1[wk]);
          c2 += fabsf(p2 - wp2[wk]);
          c3 += fabsf(p3 - wp3[wk]);
        }
      }
      v0 = -c0; v1 = -c1; v2 = -c2; v3 = -c3;
      const int opx = (rc * 7 + r) * 28 + col;
      float* op = T2 + ((size_t)(b * 64 + oc0)) * HW + opx;
      op[0] = v0; op[HW] = v1; op[2 * HW] = v2; op[3 * HW] = v3;
    }
    stats4(v0, v1, v2, v3, dS + 512, dS + 576, oc0);
  }
}

// --------------- K3: bn1 finalize + apply + relu -> padded T2b -------------
__global__ __launch_bounds__(256) void bnapply_pad_kernel(
    const float* __restrict__ T2, float* __restrict__ T2b,
    const float* __restrict__ g1, const float* __restrict__ b1,
    const double* __restrict__ dS)
{
  const int a = blockIdx.x;           // b*64 + c
  const int c = a & 63;
  __shared__ float ssc, ssb;
  if (threadIdx.x == 0){
    double s  = dS[512 + c] * (1.0 / 3136.0);
    double vr = dS[576 + c] * (1.0 / 3136.0) - s * s;
    float scale = g1[c] * rsqrtf((float)vr + 1e-5f);
    ssc = scale; ssb = b1[c] - (float)s * scale;
  }
  __syncthreads();
  const float sc_ = ssc, bi_ = ssb;
  const float* src = T2 + (size_t)a * HW;
  float* dst = T2b + (size_t)a * 960;
  for (int i = threadIdx.x; i < 960; i += 256){
    int row = i >> 5, col = i & 31;
    float v = 0.0f;
    if (row >= 1 && row <= 28 && col >= 1 && col <= 28)
      v = fmaxf(src[(row - 1) * 28 + (col - 1)] * sc_ + bi_, 0.0f);
    dst[i] = v;
  }
}

// --------------- K4: adder 3x3 over padded T2b -----------------------------
__global__ __launch_bounds__(256) void mid3x3_kernel(
    const float* __restrict__ T2b, const float* __restrict__ f_c2,
    float* __restrict__ T3, double* __restrict__ dS)
{
  const int t = threadIdx.x;
  const int a = blockIdx.x;
  const int chunk = a & 3, og = (a >> 2) & 31, b = a >> 7;
  const int oc0 = og * 2;
  const float* __restrict__ wA = f_c2 + oc0 * 576;
  const float* __restrict__ wB = wA + 576;

  float v0 = 0, v1 = 0;
  const int px = chunk * 196 + t;
  if (t < 196){
    const int y = px / 28, xc = px - y * 28;
    const float* base = T2b + (size_t)b * 64 * 960 + y * 32 + xc;
    float c0 = 0, c1 = 0;
    #pragma unroll 2
    for (int c = 0; c < 64; c++){
      const float* p = base + c * 960;
      float t0 = p[0],  t1 = p[1],  t2 = p[2];
      float t3 = p[32], t4 = p[33], t5 = p[34];
      float t6 = p[64], t7 = p[65], t8 = p[66];
      const float* wa = wA + c * 9;
      const float* wb = wB + c * 9;
      c0 += fabsf(t0 - wa[0]) + fabsf(t1 - wa[1]) + fabsf(t2 - wa[2])
          + fabsf(t3 - wa[3]) + fabsf(t4 - wa[4]) + fabsf(t5 - wa[5])
          + fabsf(t6 - wa[6]) + fabsf(t7 - wa[7]) + fabsf(t8 - wa[8]);
      c1 += fabsf(t0 - wb[0]) + fabsf(t1 - wb[1]) + fabsf(t2 - wb[2])
          + fabsf(t3 - wb[3]) + fabsf(t4 - wb[4]) + fabsf(t5 - wb[5])
          + fabsf(t6 - wb[6]) + fabsf(t7 - wb[7]) + fabsf(t8 - wb[8]);
    }
    v0 = -c0; v1 = -c1;
    T3[((size_t)(b * 64 + oc0)) * HW + px]     = v0;
    T3[((size_t)(b * 64 + oc0 + 1)) * HW + px] = v1;
  }
  stats2(v0, v1, dS + 640, dS + 704, oc0);
}

// --------------- K5: adder 1x1 64->256 (bn2 inline) ------------------------
__global__ __launch_bounds__(256) void back_kernel(
    const float* __restrict__ T3, const float* __restrict__ f_c3T,
    const float* __restrict__ g2, const float* __restrict__ b2,
    float* __restrict__ out, double* __restrict__ dS)
{
  const int t = threadIdx.x;
  const int a = blockIdx.x;
  const int chunk = a & 3, og = (a >> 2) & 63, b = a >> 8;
  const int oc0 = og * 4;
  __shared__ float ssc[64], ssb[64];
  if (t < 64){
    double s  = dS[640 + t] * (1.0 / 3136.0);
    double vr = dS[704 + t] * (1.0 / 3136.0) - s * s;
    float scale = g2[t] * rsqrtf((float)vr + 1e-5f);
    ssc[t] = scale; ssb[t] = b2[t] - (float)s * scale;
  }
  __syncthreads();

  const int px = chunk * 196 + t;
  float v0 = 0, v1 = 0, v2 = 0, v3 = 0;
  if (t < 196){
    const float* bp = T3 + (size_t)b * 64 * HW + px;
    const float* wp = f_c3T + oc0;            // row c: wp + c*256, 4 contig
    float c0 = 0, c1 = 0, c2 = 0, c3 = 0;
    #pragma unroll 4
    for (int c = 0; c < 64; c++){
      float raw = bp[(size_t)c * HW];
      float vv = fmaxf(raw * ssc[c] + ssb[c], 0.0f);
      const float* wr = wp + c * 256;         // block-uniform -> s_load
      c0 += fabsf(vv - wr[0]);
      c1 += fabsf(vv - wr[1]);
      c2 += fabsf(vv - wr[2]);
      c3 += fabsf(vv - wr[3]);
    }
    v0 = -c0; v1 = -c1; v2 = -c2; v3 = -c3;
    float* op = out + ((size_t)(b * 256 + oc0)) * HW + px;
    op[0] = v0; op[HW] = v1; op[2 * HW] = v2; op[3 * HW] = v3;
  }
  stats4(v0, v1, v2, v3, dS + 768, dS + 1024, oc0);
}

// --------------- K6: bn3 + bnds finalize, residual, relu, kl ---------------
__global__ __launch_bounds__(256) void final_kernel(
    float* __restrict__ out, const float* __restrict__ A,
    const float* __restrict__ g3, const float* __restrict__ b3,
    const float* __restrict__ gds, const float* __restrict__ bds,
    const double* __restrict__ dS)
{
  __shared__ float s3c[256], s3b[256], sdc[256], sdb[256];
  const int t = threadIdx.x;
  {
    double s  = dS[768 + t] * (1.0 / 3136.0);
    double vr = dS[1024 + t] * (1.0 / 3136.0) - s * s;
    float scale = g3[t] * rsqrtf((float)vr + 1e-5f);
    s3c[t] = scale; s3b[t] = b3[t] - (float)s * scale;
    s  = dS[t] * (1.0 / 3136.0);
    vr = dS[256 + t] * (1.0 / 3136.0) - s * s;
    scale = gds[t] * rsqrtf((float)vr + 1e-5f);
    sdc[t] = scale; sdb[t] = bds[t] - (float)s * scale;
  }
  __syncthreads();
  #pragma unroll
  for (int k = 0; k < 4; k++){
    int n = blockIdx.x * 1024 + k * 256 + t;
    int c = (n / HW) & 255;
    float h = out[n], aa = A[n];
    float r = fmaxf(aa * sdc[c] + sdb[c], 0.0f);
    out[n] = fmaxf(h * s3c[c] + s3b[c] + r, 0.0f);
  }
  if (blockIdx.x == 0){
    __shared__ double klsh[92][4];
    if (t < 92){
      klsh[t][0] = dS[1280 + t * 4];
      klsh[t][1] = dS[1280 + t * 4 + 1];
      klsh[t][2] = dS[1280 + t * 4 + 2];
      klsh[t][3] = dS[1280 + t * 4 + 3];
    }
    __syncthreads();
    if (t == 0){
      const int lo[4] = {0, 32, 40, 76};
      const int hi[4] = {32, 40, 76, 92};
      const int ns[4] = {32768, 8192, 36864, 16384};
      float kl = 0.0f;
      for (int q = 0; q < 4; q++){
        double se = 0, sel = 0, sef = 0, sq = 0;
        for (int j = lo[q]; j < hi[q]; j++){
          se += klsh[j][0]; sel += klsh[j][1];
          sef += klsh[j][2]; sq += klsh[j][3];
        }
        kl += (float)((((sel - sef) / se) - log(se) + log(sq)) / (double)ns[q]);
      }
      out[802816] = kl;
    }
  }
}

// ===========================================================================
extern "C" void kernel_launch(void* const* d_in, const int* in_sizes, int n_in,
                              void* d_out, int out_size, void* d_ws, size_t ws_size,
                              hipStream_t stream)
{
  const float* x      = (const float*)d_in[0];
  const float* sw_ds  = (const float*)d_in[1];
  const float* sw_c1  = (const float*)d_in[2];
  const float* sw_c2  = (const float*)d_in[3];
  const float* sw_c3  = (const float*)d_in[4];
  const float* a_ds   = (const float*)d_in[5];
  const float* a_c1   = (const float*)d_in[6];
  const float* a_c2   = (const float*)d_in[7];
  const float* a_c3   = (const float*)d_in[8];
  const float* peg_w  = (const float*)d_in[9];
  const float* bn1_g  = (const float*)d_in[10];
  const float* bn1_b  = (const float*)d_in[11];
  const float* bn2_g  = (const float*)d_in[12];
  const float* bn2_b  = (const float*)d_in[13];
  const float* bn3_g  = (const float*)d_in[14];
  const float* bn3_b  = (const float*)d_in[15];
  const float* bnds_g = (const float*)d_in[16];
  const float* bnds_b = (const float*)d_in[17];
  const float* lap_ds = (const float*)d_in[18];
  const float* lap_c1 = (const float*)d_in[19];
  const float* lap_c2 = (const float*)d_in[20];
  const float* lap_c3 = (const float*)d_in[21];

  float* ws    = (float*)d_ws;
  float* f_dsT = ws;                        // 32768  [c][oc] 128x256
  float* f_c1T = ws + 32768;                // 8192   [c][oc] 128x64
  float* f_c2  = ws + 40960;                // 36864  [oc][c*9+k]
  float* f_c3T = ws + 77824;                // 16384  [c][oc] 64x256
  double* dstat= (double*)(ws + 94208);     // 1648 doubles (8B aligned)
  float* A     = ws + 98304;                // 802816
  float* T2    = ws + 901120;               // 200704
  float* T3    = ws + 1101824;              // 200704
  float* T2b   = ws + 1302528;              // 245760

  float* out = (float*)d_out;

  reconkl_kernel<<<92, 256, 0, stream>>>(
      sw_ds, a_ds, lap_ds, f_dsT,
      sw_c1, a_c1, lap_c1, f_c1T,
      sw_c2, a_c2, lap_c2, f_c2,
      sw_c3, a_c3, lap_c3, f_c3T, dstat);

  front_kernel<<<768, 256, 0, stream>>>(x, f_dsT, f_c1T, peg_w, A, T2, dstat);

  bnapply_pad_kernel<<<256, 256, 0, stream>>>(T2, T2b, bn1_g, bn1_b, dstat);

  mid3x3_kernel<<<512, 256, 0, stream>>>(T2b, f_c2, T3, dstat);

  back_kernel<<<1024, 256, 0, stream>>>(T3, f_c3T, bn2_g, bn2_b, out, dstat);

  final_kernel<<<784, 256, 0, stream>>>(out, A, bn3_g, bn3_b, bnds_g, bnds_b,
                                        dstat);
}